// Round 9
// baseline (102.454 us; speedup 1.0000x reference)
//
#include <hip/hip_runtime.h>
#include <hip/hip_bf16.h>

typedef __attribute__((ext_vector_type(8))) short short8_t;   // 8 bf16
typedef __attribute__((ext_vector_type(4))) float floatx4;

__device__ __forceinline__ short bf16_of(float f) {
  __hip_bfloat16 h = __float2bfloat16(f);
  return __builtin_bit_cast(short, h);
}

__device__ __forceinline__ short8_t cvt8(float4 x, float4 y) {
  short8_t v;
  v[0] = bf16_of(x.x); v[1] = bf16_of(x.y); v[2] = bf16_of(x.z); v[3] = bf16_of(x.w);
  v[4] = bf16_of(y.x); v[5] = bf16_of(y.y); v[6] = bf16_of(y.z); v[7] = bf16_of(y.w);
  return v;
}

// ---------- async global->LDS helper (16B per lane)
__device__ __forceinline__ void gload_lds16(void* l, const void* g) {
#if defined(__has_builtin) && __has_builtin(__builtin_amdgcn_global_load_lds)
  __builtin_amdgcn_global_load_lds((const __attribute__((address_space(1))) void*)g,
                                   (__attribute__((address_space(3))) void*)l, 16, 0, 0);
#else
  *(float4*)l = *(const float4*)g;
#endif
}

// ---------- Kernel 1: fkT[oc][pd] = sum_k fb[p,o,k] * Wf[d*32+c, k] / 1024
__global__ __launch_bounds__(256) void fk_kernel(const float* __restrict__ fb,
                                                 const float* __restrict__ Wf,
                                                 float* __restrict__ fkT) {
  int gid = blockIdx.x * 256 + threadIdx.x;
#pragma unroll
  for (int i = 0; i < 4; ++i) {
    int idx = gid + i * 65536;
    int pd = idx & 511;
    int oc = idx >> 9;
    int o = oc >> 5, c = oc & 31;
    int p = pd >> 5, d = pd & 31;
    const float4* fb4 = (const float4*)(fb + (p * 16 + o) * 16);
    const float4* wf4 = (const float4*)(Wf + (d * 32 + c) * 16);
    float s = 0.f;
#pragma unroll
    for (int q = 0; q < 4; ++q) {
      float4 a = fb4[q], w = wf4[q];
      s += a.x * w.x + a.y * w.y + a.z * w.z + a.w * w.w;
    }
    fkT[idx] = s * (1.0f / 1024.0f);
  }
}

// ---------- Kernel 2: drain-free counted-vmcnt stream.
// Geometry = R6 (refcheck'd): block=(b,mt,ks), 16 m-rows x 32 n-lines; A staged via
// global_load_lds of 1KB lines (source pre-XOR'd 16B granule, ds_read same XOR).
// NEW: x-slice (contiguous 64KB) loaded to LDS ONCE in prologue -> per-iter vmem is
// ONLY the 4 staged gload_lds. Queue/wave = [S(t):4][S(t+1):4]; vmcnt(4) retires S(t)
// exactly; S(t+1) stays in flight across both barriers. No other vmem -> no drains.
__global__ __launch_bounds__(512, 2) void gemm_deep(const float* __restrict__ kb,
                                                    const float* __restrict__ x,
                                                    const float* __restrict__ Wk,
                                                    float* __restrict__ x1p) {
  __shared__ __align__(16) char lds[2][32 * 1024];   // A double buffer: 64 KB
  __shared__ __align__(16) float xlds[16384];        // x slice: 64 KB
  const int tid = threadIdx.x;
  const int bid = blockIdx.x;            // 512 = ((b*16+mt)*8)+ks
  const int ks = bid & 7;
  const int mt = (bid >> 3) & 15;
  const int b  = bid >> 7;
  const int wave = tid >> 6, lane = tid & 63;
  const int r = lane & 15, g = lane >> 4;

  // A staging: wave w, slot i -> line idx = i*8+w: n_l = idx>>4, m_l = idx&15
  const float* src[4];
  int ldsoff[4];
#pragma unroll
  for (int i = 0; i < 4; ++i) {
    int idx = i * 8 + wave;
    int n_l = idx >> 4, m_l = idx & 15;
    src[i] = kb + (size_t)(b * 256 + mt * 16 + m_l) * 65536
             + (size_t)(ks * 32 + n_l) * 256
             + (((lane * 16) ^ ((m_l & 7) << 4)) >> 2);   // pre-swizzled source
    ldsoff[i] = (n_l * 16 + m_l) * 1024 + lane * 16;      // linear LDS dest
  }

  // Wk rows r (c-half 0) and r+16 (c-half 1), k-slice (g&1)*8
  float w0[8], w1[8];
  {
    const float4* p0 = (const float4*)(Wk + r * 16 + (g & 1) * 8);
    const float4* p1 = (const float4*)(Wk + (r + 16) * 16 + (g & 1) * 8);
    float4 a = p0[0], bq = p0[1], cq = p1[0], dq = p1[1];
    w0[0] = a.x; w0[1] = a.y; w0[2] = a.z; w0[3] = a.w;
    w0[4] = bq.x; w0[5] = bq.y; w0[6] = bq.z; w0[7] = bq.w;
    w1[0] = cq.x; w1[1] = cq.y; w1[2] = cq.z; w1[3] = cq.w;
    w1[4] = dq.x; w1[5] = dq.y; w1[6] = dq.z; w1[7] = dq.w;
  }

  const int o0 = wave, o1 = wave + 8;
  floatx4 acc00 = {0.f, 0.f, 0.f, 0.f}, acc01 = {0.f, 0.f, 0.f, 0.f};
  floatx4 acc10 = {0.f, 0.f, 0.f, 0.f}, acc11 = {0.f, 0.f, 0.f, 0.f};

  // A ds_read addressing (chunk-invariant)
  const int arow = ((g >> 1) * 16 + r) * 1024;
  const int sw = (r & 7) << 4;
  const int aoff0 = o0 * 64 + (g & 1) * 32;
  const int aoff1 = o1 * 64 + (g & 1) * 32;
  // x in LDS: [n_local][o][c]; per lane n_local = (g>>1)+2t, c = half*16 + r
  const float* xb = xlds + (g >> 1) * 512 + r;

#define STAGE(buf_, t_)                                                      \
  {                                                                          \
    _Pragma("unroll") for (int i = 0; i < 4; ++i)                            \
        gload_lds16(lds[buf_] + ldsoff[i], src[i] + (size_t)(t_)*512);       \
  }
#define COMPUTE(buf_, t_)                                                    \
  {                                                                          \
    const float* px = xb + (t_) * 1024;                                      \
    float xv00 = px[o0 * 32], xv01 = px[o0 * 32 + 16];                       \
    float xv10 = px[o1 * 32], xv11 = px[o1 * 32 + 16];                       \
    const char* base = lds[buf_] + arow;                                     \
    float4 a0x = *(const float4*)(base + (aoff0 ^ sw));                      \
    float4 a0y = *(const float4*)(base + ((aoff0 + 16) ^ sw));               \
    float4 a1x = *(const float4*)(base + (aoff1 ^ sw));                      \
    float4 a1y = *(const float4*)(base + ((aoff1 + 16) ^ sw));               \
    short8_t af0 = cvt8(a0x, a0y);                                           \
    short8_t af1 = cvt8(a1x, a1y);                                           \
    short8_t b00, b01, b10, b11;                                             \
    _Pragma("unroll") for (int j = 0; j < 8; ++j) {                          \
      b00[j] = bf16_of(xv00 * w0[j]);                                        \
      b01[j] = bf16_of(xv01 * w1[j]);                                        \
      b10[j] = bf16_of(xv10 * w0[j]);                                        \
      b11[j] = bf16_of(xv11 * w1[j]);                                        \
    }                                                                        \
    acc00 = __builtin_amdgcn_mfma_f32_16x16x32_bf16(af0, b00, acc00, 0, 0, 0); \
    acc01 = __builtin_amdgcn_mfma_f32_16x16x32_bf16(af0, b01, acc01, 0, 0, 0); \
    acc10 = __builtin_amdgcn_mfma_f32_16x16x32_bf16(af1, b10, acc10, 0, 0, 0); \
    acc11 = __builtin_amdgcn_mfma_f32_16x16x32_bf16(af1, b11, acc11, 0, 0, 0); \
  }

  // prologue: x-slice (contiguous 64 KB) -> LDS, then A tile 0
  {
    const float* xsrc = x + (size_t)(b * 256 + ks * 32) * 512 + tid * 4;
    char* xdst = (char*)xlds + tid * 16;
#pragma unroll
    for (int rnd = 0; rnd < 8; ++rnd)
      gload_lds16(xdst + rnd * 8192, xsrc + (size_t)rnd * 2048);
  }
  STAGE(0, 0);   // queue: [x:8][S0:4]

  for (int t = 0; t < 16; ++t) {
    int cur = t & 1;
    if (t < 15) {
      STAGE(cur ^ 1, t + 1);                             // queue: [(x)][S(t):4][S(t+1):4]
      asm volatile("s_waitcnt vmcnt(4)" ::: "memory");   // retire thru S(t); S(t+1) flies
    } else {
      asm volatile("s_waitcnt vmcnt(0)" ::: "memory");   // last tile
    }
    __builtin_amdgcn_s_barrier();                        // raw barrier: no drain
    __builtin_amdgcn_sched_barrier(0);                   // rule #18
    COMPUTE(cur, t);
    __builtin_amdgcn_sched_barrier(0);
    __builtin_amdgcn_s_barrier();                        // all waves done reading buf[cur]
  }
#undef STAGE
#undef COMPUTE

  // C/D: col = lane&15 (c within half), row = g*4 + j (m within tile)
  float* op = x1p + (size_t)ks * 524288 + (size_t)(b * 256 + mt * 16 + g * 4) * 512 + r;
#pragma unroll
  for (int j = 0; j < 4; ++j) {
    float* rowp = op + (size_t)j * 512;
    rowp[o0 * 32]      = acc00[j];
    rowp[o0 * 32 + 16] = acc01[j];
    rowp[o1 * 32]      = acc10[j];
    rowp[o1 * 32 + 16] = acc11[j];
  }
}

// ---------- Kernel 3: out[bm, pd] = sum_oc (Σ_ks x1p[ks][bm,oc]) * fkT[oc,pd] + bias
template <int NS>
__global__ __launch_bounds__(256) void fiber_kernel(const float* __restrict__ x1p,
                                                    const float* __restrict__ fkT,
                                                    const float* __restrict__ bias,
                                                    float* __restrict__ out) {
  __shared__ float At[32][68];
  __shared__ float Bt[32][64];
  const int tid = threadIdx.x;
  const int bx = blockIdx.x & 7;
  const int by = blockIdx.x >> 3;
  const int tr = tid >> 4, tc = tid & 15;
  const int row0 = by * 64, col0 = bx * 64;
  float acc[4][4] = {};
  for (int kc = 0; kc < 512; kc += 32) {
    __syncthreads();
    {
      int r8 = tid >> 3, kq = tid & 7;
#pragma unroll
      for (int ii = 0; ii < 2; ++ii) {
        int rr = r8 + ii * 32;
        size_t off = (size_t)(row0 + rr) * 512 + kc + kq * 4;
        float4 a = *(const float4*)(x1p + off);
#pragma unroll
        for (int s = 1; s < NS; ++s) {
          float4 a2 = *(const float4*)(x1p + (size_t)s * 524288 + off);
          a.x += a2.x; a.y += a2.y; a.z += a2.z; a.w += a2.w;
        }
        At[kq * 4 + 0][rr] = a.x; At[kq * 4 + 1][rr] = a.y;
        At[kq * 4 + 2][rr] = a.z; At[kq * 4 + 3][rr] = a.w;
      }
#pragma unroll
      for (int ii = 0; ii < 2; ++ii) {
        int idx = tid + ii * 256;
        int k = idx >> 4, c4 = idx & 15;
        *(float4*)&Bt[k][c4 * 4] = *(const float4*)(fkT + (kc + k) * 512 + col0 + c4 * 4);
      }
    }
    __syncthreads();
#pragma unroll 8
    for (int k = 0; k < 32; ++k) {
      float4 av = *(const float4*)&At[k][tr * 4];
      float4 bv = *(const float4*)&Bt[k][tc * 4];
      float ar[4] = {av.x, av.y, av.z, av.w};
      float br[4] = {bv.x, bv.y, bv.z, bv.w};
#pragma unroll
      for (int i = 0; i < 4; ++i)
#pragma unroll
        for (int j = 0; j < 4; ++j)
          acc[i][j] = fmaf(ar[i], br[j], acc[i][j]);
    }
  }
  float4 bias4 = *(const float4*)(bias + ((tc * 4) & 31));
  float bb[4] = {bias4.x, bias4.y, bias4.z, bias4.w};
#pragma unroll
  for (int i = 0; i < 4; ++i) {
    float4 o4;
    o4.x = acc[i][0] + bb[0]; o4.y = acc[i][1] + bb[1];
    o4.z = acc[i][2] + bb[2]; o4.w = acc[i][3] + bb[3];
    *(float4*)(out + (size_t)(row0 + tr * 4 + i) * 512 + col0 + tc * 4) = o4;
  }
}

// ---------- fallback: single-pass direct (only if ws too small)
__global__ __launch_bounds__(256) void gemm_direct(const float* __restrict__ kb,
                                                   const float* __restrict__ x,
                                                   const float* __restrict__ Wk,
                                                   float* __restrict__ x1) {
  const int tid = threadIdx.x;
  const int bid = blockIdx.x;
  const int bo = bid & 63;
  const int b = bo >> 4, o = bo & 15;
  const int wave = tid >> 6, lane = tid & 63;
  const int mt = (bid >> 6) * 4 + wave;
  const int r = lane & 15, g = lane >> 4;
  const float* gA = kb + (size_t)(b * 256 + mt * 16 + r) * 65536
                    + (g >> 1) * 256 + o * 16 + (g & 1) * 8;
  const float* gx = x + ((size_t)(b * 256) * 16 + o) * 32 + (g >> 1) * 512 + r;
  float w0[8], w1[8];
  {
    const float4* p0 = (const float4*)(Wk + r * 16 + (g & 1) * 8);
    const float4* p1 = (const float4*)(Wk + (r + 16) * 16 + (g & 1) * 8);
    float4 a = p0[0], bq = p0[1], cq = p1[0], dq = p1[1];
    w0[0] = a.x; w0[1] = a.y; w0[2] = a.z; w0[3] = a.w;
    w0[4] = bq.x; w0[5] = bq.y; w0[6] = bq.z; w0[7] = bq.w;
    w1[0] = cq.x; w1[1] = cq.y; w1[2] = cq.z; w1[3] = cq.w;
    w1[4] = dq.x; w1[5] = dq.y; w1[6] = dq.z; w1[7] = dq.w;
  }
  floatx4 acc0 = {0.f, 0.f, 0.f, 0.f}, acc1 = {0.f, 0.f, 0.f, 0.f};
  float4 aAx, aAy, aBx, aBy;
  float xA0, xA1, xB0, xB1;
#define LOADF(sx, sy, v0, v1, kk_)                       \
  {                                                      \
    const float* pa = gA + (size_t)(kk_) * 16;           \
    sx = *(const float4*)pa;                             \
    sy = *(const float4*)(pa + 4);                       \
    const float* px = gx + (size_t)(kk_) * 32;           \
    v0 = px[0];                                          \
    v1 = px[16];                                         \
  }
#define COMPUTE(sx, sy, v0, v1)                          \
  {                                                      \
    short8_t afr = cvt8(sx, sy);                         \
    short8_t bf0, bf1;                                   \
    _Pragma("unroll") for (int j = 0; j < 8; ++j) {      \
      bf0[j] = bf16_of(v0 * w0[j]);                      \
      bf1[j] = bf16_of(v1 * w1[j]);                      \
    }                                                    \
    acc0 = __builtin_amdgcn_mfma_f32_16x16x32_bf16(afr, bf0, acc0, 0, 0, 0); \
    acc1 = __builtin_amdgcn_mfma_f32_16x16x32_bf16(afr, bf1, acc1, 0, 0, 0); \
  }
  LOADF(aAx, aAy, xA0, xA1, 0);
  for (int kk = 0; kk < 4096; kk += 64) {
    LOADF(aBx, aBy, xB0, xB1, kk + 32);
    COMPUTE(aAx, aAy, xA0, xA1);
    if (kk + 64 < 4096) LOADF(aAx, aAy, xA0, xA1, kk + 64);
    COMPUTE(aBx, aBy, xB0, xB1);
  }
#undef LOADF
#undef COMPUTE
  float* op = x1 + (size_t)(b * 256 + mt * 16 + g * 4) * 512 + o * 32 + r;
#pragma unroll
  for (int j = 0; j < 4; ++j) {
    op[(size_t)j * 512] = acc0[j];
    op[(size_t)j * 512 + 16] = acc1[j];
  }
}

extern "C" void kernel_launch(void* const* d_in, const int* in_sizes, int n_in,
                              void* d_out, int out_size, void* d_ws, size_t ws_size,
                              hipStream_t stream) {
  const float* x    = (const float*)d_in[0];  // [4,256,16,32]
  const float* kbas = (const float*)d_in[1];  // [4,256,256,16,16]
  const float* fb   = (const float*)d_in[2];  // [16,16,16]
  const float* Wk   = (const float*)d_in[3];  // [32,16]
  const float* Wf   = (const float*)d_in[4];  // [1024,16]
  const float* bias = (const float*)d_in[5];  // [32]
  float* out = (float*)d_out;                 // [4,256,16,32] f32

  float* fkT = (float*)d_ws;          // 1 MB
  float* x1p = fkT + 262144;          // 8 x 2 MB partial slices
  const size_t need = (262144 + 8 * 524288) * sizeof(float);

  fk_kernel<<<256, 256, 0, stream>>>(fb, Wf, fkT);
  if (ws_size >= need) {
    gemm_deep<<<512, 512, 0, stream>>>(kbas, x, Wk, x1p);
    fiber_kernel<8><<<128, 256, 0, stream>>>(x1p, fkT, bias, out);
  } else {
    gemm_direct<<<256, 256, 0, stream>>>(kbas, x, Wk, x1p);
    fiber_kernel<1><<<128, 256, 0, stream>>>(x1p, fkT, bias, out);
  }
}

// Round 10
// 95.626 us; speedup vs baseline: 1.0714x; 1.0714x over previous
//
#include <hip/hip_runtime.h>
#include <hip/hip_bf16.h>

typedef __attribute__((ext_vector_type(8))) short short8_t;   // 8 bf16
typedef __attribute__((ext_vector_type(4))) float floatx4;

__device__ __forceinline__ short bf16_of(float f) {
  __hip_bfloat16 h = __float2bfloat16(f);
  return __builtin_bit_cast(short, h);
}

__device__ __forceinline__ short8_t cvt8(float4 x, float4 y) {
  short8_t v;
  v[0] = bf16_of(x.x); v[1] = bf16_of(x.y); v[2] = bf16_of(x.z); v[3] = bf16_of(x.w);
  v[4] = bf16_of(y.x); v[5] = bf16_of(y.y); v[6] = bf16_of(y.z); v[7] = bf16_of(y.w);
  return v;
}

// ---------- async global->LDS helper (16B per lane)
__device__ __forceinline__ void gload_lds16(void* l, const void* g) {
#if defined(__has_builtin) && __has_builtin(__builtin_amdgcn_global_load_lds)
  __builtin_amdgcn_global_load_lds((const __attribute__((address_space(1))) void*)g,
                                   (__attribute__((address_space(3))) void*)l, 16, 0, 0);
#else
  *(float4*)l = *(const float4*)g;
#endif
}

// ---------- Kernel 1: fkT[oc][pd] = sum_k fb[p,o,k] * Wf[d*32+c, k] / 1024
__global__ __launch_bounds__(256) void fk_kernel(const float* __restrict__ fb,
                                                 const float* __restrict__ Wf,
                                                 float* __restrict__ fkT) {
  int gid = blockIdx.x * 256 + threadIdx.x;
#pragma unroll
  for (int i = 0; i < 4; ++i) {
    int idx = gid + i * 65536;
    int pd = idx & 511;
    int oc = idx >> 9;
    int o = oc >> 5, c = oc & 31;
    int p = pd >> 5, d = pd & 31;
    const float4* fb4 = (const float4*)(fb + (p * 16 + o) * 16);
    const float4* wf4 = (const float4*)(Wf + (d * 32 + c) * 16);
    float s = 0.f;
#pragma unroll
    for (int q = 0; q < 4; ++q) {
      float4 a = fb4[q], w = wf4[q];
      s += a.x * w.x + a.y * w.y + a.z * w.z + a.w * w.w;
    }
    fkT[idx] = s * (1.0f / 1024.0f);
  }
}

// ---------- Kernel 2: best-measured R6 chassis (95.8 us total).
// Block = (b, mt, ks): 16 m-rows x 32 n-lines (512 KB), each kb line fetched exactly
// once as a full contiguous 1KB global_load_lds (source pre-XOR'd at 16B granule:
// (lane*16)^((m&7)<<4); ds_read applies the same XOR). 8 waves x 2 o x 2 c-halves.
// 64 KB LDS -> 2 blocks/CU, 16 waves/CU. Runs at the measured platform read ceiling
// (~3.2 TB/s install-type streaming reads == copy-ubench read parity).
__global__ __launch_bounds__(512, 4) void gemm_stream(const float* __restrict__ kb,
                                                      const float* __restrict__ x,
                                                      const float* __restrict__ Wk,
                                                      float* __restrict__ x1p) {
  __shared__ __align__(16) char lds[2][32 * 1024];   // 2 x 32KB
  const int tid = threadIdx.x;
  const int bid = blockIdx.x;            // 512 = ((b*16+mt)*8)+ks
  const int ks = bid & 7;
  const int mt = (bid >> 3) & 15;
  const int b  = bid >> 7;
  const int wave = tid >> 6, lane = tid & 63;
  const int r = lane & 15, g = lane >> 4;

  // staging assignment: wave w, slot i -> line idx = i*8+w: n_l = idx>>4, m_l = idx&15
  const float* srcbase[4];
  int ldsoff[4];
#pragma unroll
  for (int i = 0; i < 4; ++i) {
    int idx = i * 8 + wave;
    int n_l = idx >> 4, m_l = idx & 15;
    srcbase[i] = kb + (size_t)(b * 256 + mt * 16 + m_l) * 65536
                 + (size_t)(ks * 32 + n_l) * 256
                 + (((lane * 16) ^ ((m_l & 7) << 4)) >> 2);
    ldsoff[i] = (n_l * 16 + m_l) * 1024 + lane * 16;
  }

  // Wk rows r (c-half 0) and r+16 (c-half 1), k-slice (g&1)*8
  float w0[8], w1[8];
  {
    const float4* p0 = (const float4*)(Wk + r * 16 + (g & 1) * 8);
    const float4* p1 = (const float4*)(Wk + (r + 16) * 16 + (g & 1) * 8);
    float4 a = p0[0], bq = p0[1], cq = p1[0], dq = p1[1];
    w0[0] = a.x; w0[1] = a.y; w0[2] = a.z; w0[3] = a.w;
    w0[4] = bq.x; w0[5] = bq.y; w0[6] = bq.z; w0[7] = bq.w;
    w1[0] = cq.x; w1[1] = cq.y; w1[2] = cq.z; w1[3] = cq.w;
    w1[4] = dq.x; w1[5] = dq.y; w1[6] = dq.z; w1[7] = dq.w;
  }

  const int o0 = wave, o1 = wave + 8;
  floatx4 acc00 = {0.f, 0.f, 0.f, 0.f}, acc01 = {0.f, 0.f, 0.f, 0.f};
  floatx4 acc10 = {0.f, 0.f, 0.f, 0.f}, acc11 = {0.f, 0.f, 0.f, 0.f};

  // A ds_read addressing (chunk-invariant)
  const int arow = ((g >> 1) * 16 + r) * 1024;
  const int sw = (r & 7) << 4;
  const int aoff0 = o0 * 64 + (g & 1) * 32;
  const int aoff1 = o1 * 64 + (g & 1) * 32;
  // x: [b, n, o, c]; per lane n = ks*32 + (g>>1) + 2t, c = half*16 + r
  const float* gx = x + (size_t)(b * 256 + ks * 32 + (g >> 1)) * 512 + r;

#define STAGE(buf_, t_)                                                      \
  {                                                                          \
    _Pragma("unroll") for (int i = 0; i < 4; ++i)                            \
        gload_lds16(lds[buf_] + ldsoff[i], srcbase[i] + (size_t)(t_)*512);   \
  }
#define COMPUTE(buf_, t_)                                                    \
  {                                                                          \
    const float* px = gx + (size_t)(t_)*1024;                                \
    float xv00 = px[o0 * 32], xv01 = px[o0 * 32 + 16];                       \
    float xv10 = px[o1 * 32], xv11 = px[o1 * 32 + 16];                       \
    const char* base = lds[buf_] + arow;                                     \
    float4 a0x = *(const float4*)(base + (aoff0 ^ sw));                      \
    float4 a0y = *(const float4*)(base + ((aoff0 + 16) ^ sw));               \
    float4 a1x = *(const float4*)(base + (aoff1 ^ sw));                      \
    float4 a1y = *(const float4*)(base + ((aoff1 + 16) ^ sw));               \
    short8_t af0 = cvt8(a0x, a0y);                                           \
    short8_t af1 = cvt8(a1x, a1y);                                           \
    short8_t b00, b01, b10, b11;                                             \
    _Pragma("unroll") for (int j = 0; j < 8; ++j) {                          \
      b00[j] = bf16_of(xv00 * w0[j]);                                        \
      b01[j] = bf16_of(xv01 * w1[j]);                                        \
      b10[j] = bf16_of(xv10 * w0[j]);                                        \
      b11[j] = bf16_of(xv11 * w1[j]);                                        \
    }                                                                        \
    acc00 = __builtin_amdgcn_mfma_f32_16x16x32_bf16(af0, b00, acc00, 0, 0, 0); \
    acc01 = __builtin_amdgcn_mfma_f32_16x16x32_bf16(af0, b01, acc01, 0, 0, 0); \
    acc10 = __builtin_amdgcn_mfma_f32_16x16x32_bf16(af1, b10, acc10, 0, 0, 0); \
    acc11 = __builtin_amdgcn_mfma_f32_16x16x32_bf16(af1, b11, acc11, 0, 0, 0); \
  }

  STAGE(0, 0);
  __syncthreads();
  for (int t = 0; t < 16; ++t) {
    int cur = t & 1;
    if (t < 15) STAGE(cur ^ 1, t + 1);   // issue next buffer before compute
    COMPUTE(cur, t);
    __syncthreads();                     // drains stage(t+1), protects buf reuse
  }
#undef STAGE
#undef COMPUTE

  // C/D: col = lane&15 (c within half), row = g*4 + j (m within tile)
  float* op = x1p + (size_t)ks * 524288 + (size_t)(b * 256 + mt * 16 + g * 4) * 512 + r;
#pragma unroll
  for (int j = 0; j < 4; ++j) {
    float* rowp = op + (size_t)j * 512;
    rowp[o0 * 32]      = acc00[j];
    rowp[o0 * 32 + 16] = acc01[j];
    rowp[o1 * 32]      = acc10[j];
    rowp[o1 * 32 + 16] = acc11[j];
  }
}

// ---------- Kernel 3: out[bm, pd] = sum_oc (Σ_ks x1p[ks][bm,oc]) * fkT[oc,pd] + bias
template <int NS>
__global__ __launch_bounds__(256) void fiber_kernel(const float* __restrict__ x1p,
                                                    const float* __restrict__ fkT,
                                                    const float* __restrict__ bias,
                                                    float* __restrict__ out) {
  __shared__ float At[32][68];
  __shared__ float Bt[32][64];
  const int tid = threadIdx.x;
  const int bx = blockIdx.x & 7;
  const int by = blockIdx.x >> 3;
  const int tr = tid >> 4, tc = tid & 15;
  const int row0 = by * 64, col0 = bx * 64;
  float acc[4][4] = {};
  for (int kc = 0; kc < 512; kc += 32) {
    __syncthreads();
    {
      int r8 = tid >> 3, kq = tid & 7;
#pragma unroll
      for (int ii = 0; ii < 2; ++ii) {
        int rr = r8 + ii * 32;
        size_t off = (size_t)(row0 + rr) * 512 + kc + kq * 4;
        float4 a = *(const float4*)(x1p + off);
#pragma unroll
        for (int s = 1; s < NS; ++s) {
          float4 a2 = *(const float4*)(x1p + (size_t)s * 524288 + off);
          a.x += a2.x; a.y += a2.y; a.z += a2.z; a.w += a2.w;
        }
        At[kq * 4 + 0][rr] = a.x; At[kq * 4 + 1][rr] = a.y;
        At[kq * 4 + 2][rr] = a.z; At[kq * 4 + 3][rr] = a.w;
      }
#pragma unroll
      for (int ii = 0; ii < 2; ++ii) {
        int idx = tid + ii * 256;
        int k = idx >> 4, c4 = idx & 15;
        *(float4*)&Bt[k][c4 * 4] = *(const float4*)(fkT + (kc + k) * 512 + col0 + c4 * 4);
      }
    }
    __syncthreads();
#pragma unroll 8
    for (int k = 0; k < 32; ++k) {
      float4 av = *(const float4*)&At[k][tr * 4];
      float4 bv = *(const float4*)&Bt[k][tc * 4];
      float ar[4] = {av.x, av.y, av.z, av.w};
      float br[4] = {bv.x, bv.y, bv.z, bv.w};
#pragma unroll
      for (int i = 0; i < 4; ++i)
#pragma unroll
        for (int j = 0; j < 4; ++j)
          acc[i][j] = fmaf(ar[i], br[j], acc[i][j]);
    }
  }
  float4 bias4 = *(const float4*)(bias + ((tc * 4) & 31));
  float bb[4] = {bias4.x, bias4.y, bias4.z, bias4.w};
#pragma unroll
  for (int i = 0; i < 4; ++i) {
    float4 o4;
    o4.x = acc[i][0] + bb[0]; o4.y = acc[i][1] + bb[1];
    o4.z = acc[i][2] + bb[2]; o4.w = acc[i][3] + bb[3];
    *(float4*)(out + (size_t)(row0 + tr * 4 + i) * 512 + col0 + tc * 4) = o4;
  }
}

// ---------- fallback: single-pass direct (only if ws too small)
__global__ __launch_bounds__(256) void gemm_direct(const float* __restrict__ kb,
                                                   const float* __restrict__ x,
                                                   const float* __restrict__ Wk,
                                                   float* __restrict__ x1) {
  const int tid = threadIdx.x;
  const int bid = blockIdx.x;
  const int bo = bid & 63;
  const int b = bo >> 4, o = bo & 15;
  const int wave = tid >> 6, lane = tid & 63;
  const int mt = (bid >> 6) * 4 + wave;
  const int r = lane & 15, g = lane >> 4;
  const float* gA = kb + (size_t)(b * 256 + mt * 16 + r) * 65536
                    + (g >> 1) * 256 + o * 16 + (g & 1) * 8;
  const float* gx = x + ((size_t)(b * 256) * 16 + o) * 32 + (g >> 1) * 512 + r;
  float w0[8], w1[8];
  {
    const float4* p0 = (const float4*)(Wk + r * 16 + (g & 1) * 8);
    const float4* p1 = (const float4*)(Wk + (r + 16) * 16 + (g & 1) * 8);
    float4 a = p0[0], bq = p0[1], cq = p1[0], dq = p1[1];
    w0[0] = a.x; w0[1] = a.y; w0[2] = a.z; w0[3] = a.w;
    w0[4] = bq.x; w0[5] = bq.y; w0[6] = bq.z; w0[7] = bq.w;
    w1[0] = cq.x; w1[1] = cq.y; w1[2] = cq.z; w1[3] = cq.w;
    w1[4] = dq.x; w1[5] = dq.y; w1[6] = dq.z; w1[7] = dq.w;
  }
  floatx4 acc0 = {0.f, 0.f, 0.f, 0.f}, acc1 = {0.f, 0.f, 0.f, 0.f};
  float4 aAx, aAy, aBx, aBy;
  float xA0, xA1, xB0, xB1;
#define LOADF(sx, sy, v0, v1, kk_)                       \
  {                                                      \
    const float* pa = gA + (size_t)(kk_) * 16;           \
    sx = *(const float4*)pa;                             \
    sy = *(const float4*)(pa + 4);                       \
    const float* px = gx + (size_t)(kk_) * 32;           \
    v0 = px[0];                                          \
    v1 = px[16];                                         \
  }
#define COMPUTE(sx, sy, v0, v1)                          \
  {                                                      \
    short8_t afr = cvt8(sx, sy);                         \
    short8_t bf0, bf1;                                   \
    _Pragma("unroll") for (int j = 0; j < 8; ++j) {      \
      bf0[j] = bf16_of(v0 * w0[j]);                      \
      bf1[j] = bf16_of(v1 * w1[j]);                      \
    }                                                    \
    acc0 = __builtin_amdgcn_mfma_f32_16x16x32_bf16(afr, bf0, acc0, 0, 0, 0); \
    acc1 = __builtin_amdgcn_mfma_f32_16x16x32_bf16(afr, bf1, acc1, 0, 0, 0); \
  }
  LOADF(aAx, aAy, xA0, xA1, 0);
  for (int kk = 0; kk < 4096; kk += 64) {
    LOADF(aBx, aBy, xB0, xB1, kk + 32);
    COMPUTE(aAx, aAy, xA0, xA1);
    if (kk + 64 < 4096) LOADF(aAx, aAy, xA0, xA1, kk + 64);
    COMPUTE(aBx, aBy, xB0, xB1);
  }
#undef LOADF
#undef COMPUTE
  float* op = x1 + (size_t)(b * 256 + mt * 16 + g * 4) * 512 + o * 32 + r;
#pragma unroll
  for (int j = 0; j < 4; ++j) {
    op[(size_t)j * 512] = acc0[j];
    op[(size_t)j * 512 + 16] = acc1[j];
  }
}

extern "C" void kernel_launch(void* const* d_in, const int* in_sizes, int n_in,
                              void* d_out, int out_size, void* d_ws, size_t ws_size,
                              hipStream_t stream) {
  const float* x    = (const float*)d_in[0];  // [4,256,16,32]
  const float* kbas = (const float*)d_in[1];  // [4,256,256,16,16]
  const float* fb   = (const float*)d_in[2];  // [16,16,16]
  const float* Wk   = (const float*)d_in[3];  // [32,16]
  const float* Wf   = (const float*)d_in[4];  // [1024,16]
  const float* bias = (const float*)d_in[5];  // [32]
  float* out = (float*)d_out;                 // [4,256,16,32] f32

  float* fkT = (float*)d_ws;          // 1 MB
  float* x1p = fkT + 262144;          // 8 x 2 MB partial slices
  const size_t need = (262144 + 8 * 524288) * sizeof(float);

  fk_kernel<<<256, 256, 0, stream>>>(fb, Wf, fkT);
  if (ws_size >= need) {
    gemm_stream<<<512, 512, 0, stream>>>(kbas, x, Wk, x1p);
    fiber_kernel<8><<<128, 256, 0, stream>>>(x1p, fkT, bias, out);
  } else {
    gemm_direct<<<256, 256, 0, stream>>>(kbas, x, Wk, x1p);
    fiber_kernel<1><<<128, 256, 0, stream>>>(x1p, fkT, bias, out);
  }
}